// Round 1
// baseline (13972.237 us; speedup 1.0000x reference)
//
#include <hip/hip_runtime.h>
#include <math.h>

#define DDIM 16
#define NSTEPS 64

__device__ __forceinline__ float gelu_exact(float x) {
    // torch.nn.GELU default: 0.5*x*(1+erf(x/sqrt(2)))
    return 0.5f * x * (1.0f + erff(x * 0.70710678118654752440f));
}

__global__ __launch_bounds__(256) void resnet_steps_kernel(
    const float* __restrict__ x,
    const float* __restrict__ W,
    const float* __restrict__ V,
    float* __restrict__ out,
    int batch)
{
    int row = blockIdx.x * blockDim.x + threadIdx.x;
    if (row >= batch) return;

    // Load this row's h[16] with float4 vector loads (64B/thread).
    float h[DDIM];
    const float4* xv = reinterpret_cast<const float4*>(x + (size_t)row * DDIM);
    #pragma unroll
    for (int i = 0; i < 4; ++i) {
        float4 v = xv[i];
        h[4*i+0] = v.x; h[4*i+1] = v.y; h[4*i+2] = v.z; h[4*i+3] = v.w;
    }

    const float inv_n = 1.0f / (float)NSTEPS;

    // 64 sequential steps; W/V addresses are wave-uniform (depend only on s
    // and compile-time indices) -> compiler emits s_load broadcasts, vector
    // pipe stays free for the 512 FMAs/step.
    for (int s = 0; s < NSTEPS; ++s) {
        const float* __restrict__ Wi = W + s * DDIM * DDIM;
        const float* __restrict__ Vi = V + s * DDIM * DDIM;

        float u[DDIM];
        #pragma unroll
        for (int j = 0; j < DDIM; ++j) u[j] = 0.0f;

        // u = h @ W_s   (u[j] += h[k] * W[k][j]; 16 independent acc chains)
        #pragma unroll
        for (int k = 0; k < DDIM; ++k) {
            float hk = h[k];
            #pragma unroll
            for (int j = 0; j < DDIM; ++j)
                u[j] = fmaf(hk, Wi[k*DDIM + j], u[j]);
        }

        // g = GELU(u) * (1/N)   (fold the residual scale in here)
        #pragma unroll
        for (int j = 0; j < DDIM; ++j)
            u[j] = gelu_exact(u[j]) * inv_n;

        // h += g @ V_s
        #pragma unroll
        for (int k = 0; k < DDIM; ++k) {
            float gk = u[k];
            #pragma unroll
            for (int j = 0; j < DDIM; ++j)
                h[j] = fmaf(gk, Vi[k*DDIM + j], h[j]);
        }
    }

    float4* ov = reinterpret_cast<float4*>(out + (size_t)row * DDIM);
    #pragma unroll
    for (int i = 0; i < 4; ++i)
        ov[i] = make_float4(h[4*i+0], h[4*i+1], h[4*i+2], h[4*i+3]);
}

extern "C" void kernel_launch(void* const* d_in, const int* in_sizes, int n_in,
                              void* d_out, int out_size, void* d_ws, size_t ws_size,
                              hipStream_t stream) {
    const float* x = (const float*)d_in[0];   // [B, 16] fp32
    const float* W = (const float*)d_in[1];   // [64, 16, 16] fp32
    const float* V = (const float*)d_in[2];   // [64, 16, 16] fp32
    float* out = (float*)d_out;               // [B, 16] fp32

    int batch = in_sizes[0] / DDIM;           // 2^21
    dim3 block(256);
    dim3 grid((batch + 255) / 256);
    resnet_steps_kernel<<<grid, block, 0, stream>>>(x, W, V, out, batch);
}

// Round 2
// 2024.985 us; speedup vs baseline: 6.8999x; 6.8999x over previous
//
#include <hip/hip_runtime.h>
#include <math.h>

#define DDIM 16
#define NSTEPS 64

// tanh-form GELU, computed as x * sigmoid(2*c0*(x + c1*x^3)).
// tanh(y) = 1 - 2/(1+e^{2y})  =>  0.5*(1+tanh(y)) = 1 - 1/(1+e^{2y}).
// K folds c0 and the exp->exp2 conversion: K = c0 * 2 * log2(e).
// ~10 straight-line VALU ops, no divergence, no IEEE divide sequence.
__device__ __forceinline__ float gelu_fast(float x) {
    const float c1 = 0.044715f;
    const float K  = 2.3022082f;   // 0.7978845608 * 2.8853900818
    float x2 = x * x;
    float z  = x * fmaf(c1, x2, 1.0f);      // x + c1*x^3
    float e  = __builtin_amdgcn_exp2f(z * K);
    float r  = __builtin_amdgcn_rcpf(1.0f + e);
    return x * (1.0f - r);
}

__global__ __launch_bounds__(256) void resnet_steps_kernel(
    const float* __restrict__ x,
    const float* __restrict__ W,
    const float* __restrict__ V,
    float* __restrict__ out,
    int batch)
{
    int row = blockIdx.x * blockDim.x + threadIdx.x;
    if (row >= batch) return;

    float h[DDIM];
    const float4* xv = reinterpret_cast<const float4*>(x + (size_t)row * DDIM);
    #pragma unroll
    for (int i = 0; i < 4; ++i) {
        float4 v = xv[i];
        h[4*i+0] = v.x; h[4*i+1] = v.y; h[4*i+2] = v.z; h[4*i+3] = v.w;
    }

    const float inv_n = 1.0f / (float)NSTEPS;

    for (int s = 0; s < NSTEPS; ++s) {
        // Wi/Vi addresses depend only on the uniform loop index -> scalar
        // (s_load_dwordx4) loads; vector pipe stays free for FMAs.
        const float* __restrict__ Wi = W + s * DDIM * DDIM;
        const float* __restrict__ Vi = V + s * DDIM * DDIM;

        float u[DDIM];
        #pragma unroll
        for (int j = 0; j < DDIM; ++j) u[j] = 0.0f;

        // u = h @ W_s
        #pragma unroll
        for (int k = 0; k < DDIM; ++k) {
            const float4* wr = reinterpret_cast<const float4*>(Wi + k * DDIM);
            float hk = h[k];
            #pragma unroll
            for (int q = 0; q < 4; ++q) {
                float4 w = wr[q];
                u[4*q+0] = fmaf(hk, w.x, u[4*q+0]);
                u[4*q+1] = fmaf(hk, w.y, u[4*q+1]);
                u[4*q+2] = fmaf(hk, w.z, u[4*q+2]);
                u[4*q+3] = fmaf(hk, w.w, u[4*q+3]);
            }
        }

        // g = GELU(u) * (1/N)  (residual scale folded in)
        #pragma unroll
        for (int j = 0; j < DDIM; ++j)
            u[j] = gelu_fast(u[j]) * inv_n;

        // h += g @ V_s
        #pragma unroll
        for (int k = 0; k < DDIM; ++k) {
            const float4* vr = reinterpret_cast<const float4*>(Vi + k * DDIM);
            float gk = u[k];
            #pragma unroll
            for (int q = 0; q < 4; ++q) {
                float4 v = vr[q];
                h[4*q+0] = fmaf(gk, v.x, h[4*q+0]);
                h[4*q+1] = fmaf(gk, v.y, h[4*q+1]);
                h[4*q+2] = fmaf(gk, v.z, h[4*q+2]);
                h[4*q+3] = fmaf(gk, v.w, h[4*q+3]);
            }
        }
    }

    float4* ov = reinterpret_cast<float4*>(out + (size_t)row * DDIM);
    #pragma unroll
    for (int i = 0; i < 4; ++i)
        ov[i] = make_float4(h[4*i+0], h[4*i+1], h[4*i+2], h[4*i+3]);
}

extern "C" void kernel_launch(void* const* d_in, const int* in_sizes, int n_in,
                              void* d_out, int out_size, void* d_ws, size_t ws_size,
                              hipStream_t stream) {
    const float* x = (const float*)d_in[0];   // [B, 16] fp32
    const float* W = (const float*)d_in[1];   // [64, 16, 16] fp32
    const float* V = (const float*)d_in[2];   // [64, 16, 16] fp32
    float* out = (float*)d_out;               // [B, 16] fp32

    int batch = in_sizes[0] / DDIM;           // 2^21
    dim3 block(256);
    dim3 grid((batch + 255) / 256);
    resnet_steps_kernel<<<grid, block, 0, stream>>>(x, W, V, out, batch);
}

// Round 4
// 1001.779 us; speedup vs baseline: 13.9474x; 2.0214x over previous
//
#include <hip/hip_runtime.h>
#include <math.h>

#define DDIM 16
#define NSTEPS 64

typedef _Float16 half4  __attribute__((ext_vector_type(4)));
typedef float    floatx4 __attribute__((ext_vector_type(4)));

// ---------------------------------------------------------------------------
// Pre-pack W^T / V^T into per-lane MFMA A-operand fragments (f16).
// For v_mfma_f32_16x16x16_f16, A[m][k]: lane L supplies m = L&15, k = 4*(L>>4)+j.
// We feed A = W_s^T, so lane L, elem j holds W_s^T[L&15][4q+j] = W_s[4q+j][L&15].
// Fragment for (step s, lane L) stored contiguously at pw[s*64 + L] (8 bytes).
// ---------------------------------------------------------------------------
__global__ __launch_bounds__(256) void pack_wv(const float* __restrict__ W,
                                               const float* __restrict__ V,
                                               half4* __restrict__ pw,
                                               half4* __restrict__ pv)
{
    int t = blockIdx.x * 256 + threadIdx.x;   // 0..4095 = 64 steps * 64 lanes
    int L = t & 63;
    int s = t >> 6;
    int q = L >> 4, r = L & 15;
    const float* Ws = W + s * DDIM * DDIM;
    const float* Vs = V + s * DDIM * DDIM;
    half4 w, v;
    #pragma unroll
    for (int j = 0; j < 4; ++j) {
        w[j] = (_Float16)Ws[(4 * q + j) * DDIM + r];
        v[j] = (_Float16)Vs[(4 * q + j) * DDIM + r];
    }
    pw[t] = w;
    pv[t] = v;
}

// ---------------------------------------------------------------------------
// Main kernel: each wave owns 4 row-tiles (64 rows). State h kept in fp32 in
// the MFMA C/D layout: lane L holds h[row = L&15][cols 4q..4q+3] of its tile.
// Chain (all transposed):  u^T = W^T @ h^T ;  h^T += V^T @ (gelu(u)/N)^T.
// C/D layout == B-operand layout for the transposed chain -> no shuffles/LDS.
// ---------------------------------------------------------------------------
__global__ __launch_bounds__(256) void resnet_mfma_kernel(
    const float* __restrict__ x,
    const half4* __restrict__ pw,
    const half4* __restrict__ pv,
    float* __restrict__ out)
{
    const int tid  = threadIdx.x;
    const int lane = tid & 63;
    const int wave = tid >> 6;
    const int q = lane >> 4, r = lane & 15;

    const long rowbase = (long)blockIdx.x * 256 + (long)wave * 64;

    // Load state: lane reads float4 at (row, 4q) for each of its 4 tiles.
    floatx4 h[4];
    #pragma unroll
    for (int t = 0; t < 4; ++t) {
        const float4* p = reinterpret_cast<const float4*>(
            x + (rowbase + t * 16 + r) * DDIM + 4 * q);
        float4 v = *p;
        h[t][0] = v.x; h[t][1] = v.y; h[t][2] = v.z; h[t][3] = v.w;
    }

    const float inv_n = 1.0f / (float)NSTEPS;
    const float c1 = 0.044715f;
    const float K  = 2.3022082f;   // 0.7978845608 * 2 * log2(e)

    // Software-prefetch the W/V fragments one step ahead (L1/L2-hot, 64KB total).
    half4 wf = pw[lane];
    half4 vf = pv[lane];

    for (int s = 0; s < NSTEPS; ++s) {
        int sn = (s < NSTEPS - 1) ? s + 1 : s;
        half4 wfn = pw[sn * 64 + lane];
        half4 vfn = pv[sn * 64 + lane];

        #pragma unroll
        for (int t = 0; t < 4; ++t) {
            // h (fp32, C/D layout) -> f16 B-operand (scalar cvt, compiler packs)
            half4 hb;
            #pragma unroll
            for (int j = 0; j < 4; ++j) hb[j] = (_Float16)h[t][j];

            floatx4 zero = {0.f, 0.f, 0.f, 0.f};
            floatx4 u = __builtin_amdgcn_mfma_f32_16x16x16f16(wf, hb, zero, 0, 0, 0);

            // g = GELU(u) * (1/N), elementwise (layout-agnostic)
            float g[4];
            #pragma unroll
            for (int j = 0; j < 4; ++j) {
                float xv = u[j];
                float z  = (xv * K) * fmaf(c1, xv * xv, 1.0f);  // K*(x + c1 x^3)
                float e  = __builtin_amdgcn_exp2f(z);
                float rr = __builtin_amdgcn_rcpf(1.0f + e);
                float p  = xv * inv_n;
                g[j] = fmaf(-p, rr, p);                          // x*(1-r)*inv_n
            }
            half4 gb;
            #pragma unroll
            for (int j = 0; j < 4; ++j) gb[j] = (_Float16)g[j];

            // h += g @ V  (residual add folded into MFMA C operand, fp32)
            h[t] = __builtin_amdgcn_mfma_f32_16x16x16f16(vf, gb, h[t], 0, 0, 0);
        }

        wf = wfn; vf = vfn;
    }

    #pragma unroll
    for (int t = 0; t < 4; ++t) {
        float4 v = make_float4(h[t][0], h[t][1], h[t][2], h[t][3]);
        *reinterpret_cast<float4*>(out + (rowbase + t * 16 + r) * DDIM + 4 * q) = v;
    }
}

extern "C" void kernel_launch(void* const* d_in, const int* in_sizes, int n_in,
                              void* d_out, int out_size, void* d_ws, size_t ws_size,
                              hipStream_t stream) {
    const float* x = (const float*)d_in[0];   // [B, 16] fp32
    const float* W = (const float*)d_in[1];   // [64, 16, 16] fp32
    const float* V = (const float*)d_in[2];   // [64, 16, 16] fp32
    float* out = (float*)d_out;

    half4* pw = (half4*)d_ws;                 // 64 steps * 64 lanes * 8B = 32KB
    half4* pv = pw + NSTEPS * 64;             // +32KB (ws_size must be >= 64KB)

    pack_wv<<<16, 256, 0, stream>>>(W, V, pw, pv);

    int batch = in_sizes[0] / DDIM;           // 2^21
    resnet_mfma_kernel<<<batch / 256, 256, 0, stream>>>(x, pw, pv, out);
}